// Round 2
// baseline (1458.060 us; speedup 1.0000x reference)
//
#include <hip/hip_runtime.h>

// Problem constants: STATE=4096, CDIM=1024, fan_in=5121, T integrated with RK4.
#define FAN   5121
#define N     4096
#define NC    1024
#define STEPS 4
#define RCH   32      // row chunks per matvec (grid.y of k_mv_part)
#define TPB   256

__device__ __forceinline__ float sigf(float x) { return 1.0f / (1.0f + __expf(-x)); }

// ---------------------------------------------------------------------------
// init: xbuf = [c, sig(h), t0=0]; ycur = h; rk[0..15] = 0
// ---------------------------------------------------------------------------
__global__ __launch_bounds__(TPB) void k_init(const float* __restrict__ h,
                                              const float* __restrict__ c,
                                              float* __restrict__ xbuf,
                                              float* __restrict__ ycur,
                                              float* __restrict__ rk) {
  const int j = blockIdx.x * TPB + threadIdx.x;
  if (j < NC) xbuf[j] = c[j];
  if (j < N) {
    const float hv = h[j];
    ycur[j] = hv;
    xbuf[NC + j] = sigf(hv);
  }
  if (j == 0) xbuf[NC + N] = 0.f;   // t = 0 at start
  if (j < 16) rk[j] = 0.f;
}

// ---------------------------------------------------------------------------
// Partial matvec: out_part[chunk][j] = sum_{i in chunk} x[i] * W[i][j]
// W is [FAN][N] row-major fp32 (native layout). Block = 256 thr = 4 waves;
// each wave takes rows i = c0 + w + 4k (one full row per iteration, lanes
// read 64 consecutive float4 = 1 KB coalesced). Lane covers 4 columns.
// xrow is a pointer such that row i's x value is xrow[i].
// ---------------------------------------------------------------------------
__global__ __launch_bounds__(TPB) void k_mv_part(const float* __restrict__ W,
                                                 const float* __restrict__ xrow,
                                                 float* __restrict__ part,
                                                 int rowStart, int nRows) {
  __shared__ float xs[192];
  __shared__ float red[4][256];
  const int tid = threadIdx.x;
  const int w = tid >> 6, l = tid & 63;
  const int colbase = blockIdx.x * 256;
  const int chunk = (nRows + RCH - 1) / RCH;
  const int c0 = blockIdx.y * chunk;
  const int c1 = min(c0 + chunk, nRows);
  const int nch = c1 - c0;
  if (tid < nch) xs[tid] = xrow[rowStart + c0 + tid];
  __syncthreads();

  float a0 = 0.f, a1 = 0.f, a2 = 0.f, a3 = 0.f;
  for (int i = w; i < nch; i += 4) {
    const float xv = xs[i];
    const float4 wv = *reinterpret_cast<const float4*>(
        W + (size_t)(rowStart + c0 + i) * N + colbase + 4 * l);
    a0 = fmaf(xv, wv.x, a0);
    a1 = fmaf(xv, wv.y, a1);
    a2 = fmaf(xv, wv.z, a2);
    a3 = fmaf(xv, wv.w, a3);
  }
  red[w][4 * l + 0] = a0;
  red[w][4 * l + 1] = a1;
  red[w][4 * l + 2] = a2;
  red[w][4 * l + 3] = a3;
  __syncthreads();
  const float s = red[0][tid] + red[1][tid] + red[2][tid] + red[3][tid];
  part[(size_t)blockIdx.y * N + colbase + tid] = s;
}

// ---------------------------------------------------------------------------
// R1: u1 = reduce(part) + b1;  xbuf middle = sig(u1)   (x2 for layer 2)
// ---------------------------------------------------------------------------
__global__ __launch_bounds__(TPB) void k_r1(const float* __restrict__ part,
                                            const float* __restrict__ b1,
                                            float* __restrict__ u1,
                                            float* __restrict__ xbuf) {
  const int j = blockIdx.x * TPB + threadIdx.x;
  float s = b1[j];
  for (int r = 0; r < RCH; ++r) s += part[(size_t)r * N + j];
  u1[j] = s;
  xbuf[NC + j] = sigf(s);
}

// ---------------------------------------------------------------------------
// R2: fcur = reduce(part) + b2;  v1 = sig'(ystage) * fcur  (tangent L1 input)
// ystage = ycur + csv*dt*fprev (for s==0 pass fprev=ycur, csv=0).
// ---------------------------------------------------------------------------
__global__ __launch_bounds__(TPB) void k_r2(const float* __restrict__ part,
                                            const float* __restrict__ b2,
                                            const float* __restrict__ ycur,
                                            const float* __restrict__ fprev,
                                            const float* __restrict__ tptr,
                                            float csv,
                                            float* __restrict__ fcur,
                                            float* __restrict__ vbuf) {
  const int j = blockIdx.x * TPB + threadIdx.x;
  float s = b2[j];
  for (int r = 0; r < RCH; ++r) s += part[(size_t)r * N + j];
  fcur[j] = s;
  const float dt = tptr[0] * (1.0f / STEPS);
  const float ys = fmaf(csv * dt, fprev[j], ycur[j]);
  const float s0 = sigf(ys);
  vbuf[j] = s0 * (1.f - s0) * s;
  if (j == 0) vbuf[N] = 1.0f;   // t-row tangent coefficient
}

// ---------------------------------------------------------------------------
// R3: du1 = reduce(part);  v2 = sig'(u1) * du1  (tangent L2 input)
// ---------------------------------------------------------------------------
__global__ __launch_bounds__(TPB) void k_r3(const float* __restrict__ part,
                                            const float* __restrict__ u1,
                                            float* __restrict__ vbuf) {
  const int j = blockIdx.x * TPB + threadIdx.x;
  float s = 0.f;
  for (int r = 0; r < RCH; ++r) s += part[(size_t)r * N + j];
  const float s1 = sigf(u1[j]);
  vbuf[j] = s1 * (1.f - s1) * s;
  if (j == 0) vbuf[N] = 1.0f;
}

// ---------------------------------------------------------------------------
// F: df = reduce(part); accumulate sum(df^2) into rk[sidx]; RK4 bookkeeping on
// ksum/ycur using fcur; build next stage's x1 = sig(y_next_stage_base).
// ---------------------------------------------------------------------------
__global__ __launch_bounds__(TPB) void k_fin(const float* __restrict__ part,
                                             const float* __restrict__ tptr,
                                             const float* __restrict__ fcur,
                                             float* __restrict__ ycur,
                                             float* __restrict__ ksum,
                                             float* __restrict__ xbuf,
                                             float* __restrict__ rk,
                                             int sidx, int s,
                                             float csv_next, float tnext_scale) {
  __shared__ float red[4];
  const int tid = threadIdx.x;
  const int j = blockIdx.x * TPB + tid;
  float df = 0.f;
  for (int r = 0; r < RCH; ++r) df += part[(size_t)r * N + j];

  float v = df * df;
  for (int off = 32; off >= 1; off >>= 1) v += __shfl_down(v, off);
  if ((tid & 63) == 0) red[tid >> 6] = v;
  __syncthreads();
  if (tid == 0) atomicAdd(&rk[sidx], red[0] + red[1] + red[2] + red[3]);

  const float dt = tptr[0] * (1.0f / STEPS);
  const float fc = fcur[j];
  float y = ycur[j];
  if (s == 0)      ksum[j] = fc;
  else if (s < 3)  ksum[j] = fmaf(2.f, fc, ksum[j]);
  else { y = fmaf(dt * (1.f / 6.f), ksum[j] + fc, y); ycur[j] = y; }

  // next stage base: within a step fprev_next = fc; across steps csv_next = 0.
  const float ysn = fmaf(csv_next * dt, fc, y);
  xbuf[NC + j] = sigf(ysn);
  if (j == 0) xbuf[NC + N] = tnext_scale * dt;
}

// ---------------------------------------------------------------------------
// final: out[0..N) = ycur; out[N] = RK4-weighted integral of mean(df^2)
// ---------------------------------------------------------------------------
__global__ __launch_bounds__(TPB) void k_final(const float* __restrict__ ycur,
                                               const float* __restrict__ rk,
                                               const float* __restrict__ tptr,
                                               float* __restrict__ out) {
  const int j = blockIdx.x * TPB + threadIdx.x;
  if (j < N) out[j] = ycur[j];
  if (j == 0) {
    const float dt = tptr[0] * (1.0f / STEPS);
    float r = 0.f;
    for (int st = 0; st < STEPS; ++st)
      r += rk[4 * st] + 2.f * rk[4 * st + 1] + 2.f * rk[4 * st + 2] + rk[4 * st + 3];
    out[N] = r * (dt / 6.f) * (1.0f / N);
  }
}

// ---------------------------------------------------------------------------
extern "C" void kernel_launch(void* const* d_in, const int* in_sizes, int n_in,
                              void* d_out, int out_size, void* d_ws, size_t ws_size,
                              hipStream_t stream) {
  // setup_inputs order: h, t, c, W1, b1, W2, b2 (all fp32)
  const float* h  = (const float*)d_in[0];
  const float* t  = (const float*)d_in[1];
  const float* c  = (const float*)d_in[2];
  const float* W1 = (const float*)d_in[3];
  const float* b1 = (const float*)d_in[4];
  const float* W2 = (const float*)d_in[5];
  const float* b2 = (const float*)d_in[6];
  float* out = (float*)d_out;

  // ws layout (fp32), total ~630 KB:
  float* ws   = (float*)d_ws;
  float* part = ws;                       // RCH*N = 32*4096
  float* xbuf = part + (size_t)RCH * N;   // 5121 (pad to 5128)
  float* vbuf = xbuf + 5128;              // 4097 (pad to 4104)
  float* u1   = vbuf + 4104;
  float* f0   = u1 + N;
  float* f1   = f0 + N;
  float* ksum = f1 + N;
  float* ycur = ksum + N;
  float* rk   = ycur + N;                 // 16

  k_init<<<16, TPB, 0, stream>>>(h, c, xbuf, ycur, rk);

  const float csv[4] = {0.f, 0.5f, 0.5f, 1.f};
  for (int step = 0; step < STEPS; ++step) {
    for (int s = 0; s < 4; ++s) {
      float* fcur = (s & 1) ? f1 : f0;
      float* fprev = (s & 1) ? f0 : f1;
      const float* fprev_use = (s == 0) ? ycur : fprev;  // ×0 when s==0

      // P1: u1 = x1 @ W1 (full rows)
      k_mv_part<<<dim3(16, RCH), TPB, 0, stream>>>(W1, xbuf, part, 0, FAN);
      k_r1<<<16, TPB, 0, stream>>>(part, b1, u1, xbuf);
      // P2: f = x2 @ W2 (full rows)
      k_mv_part<<<dim3(16, RCH), TPB, 0, stream>>>(W2, xbuf, part, 0, FAN);
      k_r2<<<16, TPB, 0, stream>>>(part, b2, ycur, fprev_use, t, csv[s], fcur, vbuf);
      // P3: du1 = v1 @ W1 (state rows + t-row): rows [NC, FAN)
      k_mv_part<<<dim3(16, RCH), TPB, 0, stream>>>(W1, vbuf - NC, part, NC, FAN - NC);
      k_r3<<<16, TPB, 0, stream>>>(part, u1, vbuf);
      // P4: df = v2 @ W2 (state rows + t-row)
      k_mv_part<<<dim3(16, RCH), TPB, 0, stream>>>(W2, vbuf - NC, part, NC, FAN - NC);
      const int snext = (s + 1) & 3;
      const int stepn = (s == 3) ? step + 1 : step;
      k_fin<<<16, TPB, 0, stream>>>(part, t, fcur, ycur, ksum, xbuf, rk,
                                    step * 4 + s, s, csv[snext],
                                    (float)stepn + csv[snext]);
    }
  }
  k_final<<<17, TPB, 0, stream>>>(ycur, rk, t, out);
}

// Round 3
// 851.153 us; speedup vs baseline: 1.7130x; 1.7130x over previous
//
#include <hip/hip_runtime.h>

// STATE=4096, CDIM=1024, fan_in=5121. RK4 x 4 steps = 16 aug-dynamics evals.
// Weights: state rows + t-row (4097 x 4096) cached in ws as bf16; c-rows'
// contribution (+bias) precomputed once in fp32 (cpart1/2).
#define N      4096
#define NROWS  4097
#define NC     1024
#define STEPS  4
#define TPB    256

typedef unsigned short us8 __attribute__((ext_vector_type(8)));

__device__ __forceinline__ float bf2f(unsigned short u) {
  union { unsigned int i; float f; } v; v.i = ((unsigned int)u) << 16; return v.f;
}
__device__ __forceinline__ unsigned short f2bf(float f) {
  union { float f; unsigned int i; } v; v.f = f;
  const unsigned int u = v.i;
  return (unsigned short)((u + 0x7FFFu + ((u >> 16) & 1u)) >> 16);  // RNE
}
__device__ __forceinline__ float sigf(float x) { return 1.0f / (1.0f + __expf(-x)); }

// ---------------------------------------------------------------------------
__global__ __launch_bounds__(TPB) void k_init(const float* __restrict__ h,
                                              const float* __restrict__ b1,
                                              const float* __restrict__ b2,
                                              float* __restrict__ ycur,
                                              float* __restrict__ cp1,
                                              float* __restrict__ cp2,
                                              float* __restrict__ rk) {
  const int j = blockIdx.x * TPB + threadIdx.x;
  if (j < N) { ycur[j] = h[j]; cp1[j] = b1[j]; cp2[j] = b2[j]; }
  if (j < 16) rk[j] = 0.f;
}

// W rows [NC, NC+NROWS) fp32 -> bf16 (native [NROWS][N] layout, RNE).
__global__ __launch_bounds__(TPB) void k_conv(const float* __restrict__ W1,
                                              const float* __restrict__ W2,
                                              unsigned short* __restrict__ W1bf,
                                              unsigned short* __restrict__ W2bf) {
  const int row = blockIdx.x;   // 0..NROWS-1
  const float* __restrict__ src = (blockIdx.y ? W2 : W1) + (size_t)(NC + row) * N;
  unsigned short* __restrict__ dst = (blockIdx.y ? W2bf : W1bf) + (size_t)row * N;
#pragma unroll
  for (int it = 0; it < 2; ++it) {
    const int col = it * 2048 + threadIdx.x * 8;
    const float4 a = *reinterpret_cast<const float4*>(src + col);
    const float4 b = *reinterpret_cast<const float4*>(src + col + 4);
    us8 o;
    o[0] = f2bf(a.x); o[1] = f2bf(a.y); o[2] = f2bf(a.z); o[3] = f2bf(a.w);
    o[4] = f2bf(b.x); o[5] = f2bf(b.y); o[6] = f2bf(b.z); o[7] = f2bf(b.w);
    *reinterpret_cast<us8*>(dst + col) = o;
  }
}

// cp += c @ W[0:NC]  (fp32, once). grid (16, 8, 2), block 256.
__global__ __launch_bounds__(TPB) void k_cpart(const float* __restrict__ W1,
                                               const float* __restrict__ W2,
                                               const float* __restrict__ c,
                                               float* __restrict__ cp1,
                                               float* __restrict__ cp2) {
  const float* __restrict__ W = blockIdx.z ? W2 : W1;
  float* __restrict__ cp = blockIdx.z ? cp2 : cp1;
  __shared__ float xs[128];
  __shared__ float red[8][256];
  const int tid = threadIdx.x;
  const int cb = blockIdx.x, rc = blockIdx.y;
  const int r0 = rc * 128;
  if (tid < 128) xs[tid] = c[r0 + tid];
  __syncthreads();
  const int cg = tid & 31, rg = tid >> 5;
  const float* __restrict__ wbase = W + (size_t)r0 * N + cb * 256 + cg * 8;
  float a[8] = {0,0,0,0,0,0,0,0};
#pragma unroll
  for (int k = 0; k < 16; ++k) {
    const int r = rg + (k << 3);
    const float xv = xs[r];
    const float4 wa = *reinterpret_cast<const float4*>(wbase + (size_t)r * N);
    const float4 wb = *reinterpret_cast<const float4*>(wbase + (size_t)r * N + 4);
    a[0] = fmaf(wa.x, xv, a[0]); a[1] = fmaf(wa.y, xv, a[1]);
    a[2] = fmaf(wa.z, xv, a[2]); a[3] = fmaf(wa.w, xv, a[3]);
    a[4] = fmaf(wb.x, xv, a[4]); a[5] = fmaf(wb.y, xv, a[5]);
    a[6] = fmaf(wb.z, xv, a[6]); a[7] = fmaf(wb.w, xv, a[7]);
  }
#pragma unroll
  for (int e = 0; e < 8; ++e) red[rg][cg * 8 + e] = a[e];
  __syncthreads();
  float ssum = 0.f;
#pragma unroll
  for (int g = 0; g < 8; ++g) ssum += red[g][tid];
  atomicAdd(&cp[cb * 256 + tid], ssum);
}

// ---------------------------------------------------------------------------
// One fused phase: reduce previous partials for my 128-row chunk -> epilogue
// (per mode) -> build x chunk -> matvec over bf16 weights -> write partials.
// Modes: 0=FIRST(x=sig(h)), 1=P2(u1), 2=P3(f,tangent-L1 in), 3=P4(du1,RK),
//        4=PD(df,rk,next-stage x1). grid (16 colblocks, 32 rowchunks).
// ---------------------------------------------------------------------------
__global__ __launch_bounds__(TPB) void k_phase(
    int mode,
    const unsigned short* __restrict__ Wbf,
    const float* __restrict__ part_in,
    float* __restrict__ part_out,
    const float* __restrict__ cpart,
    const float* __restrict__ tptr,
    float* __restrict__ u1,
    float* __restrict__ fcur,
    const float* __restrict__ fprev,
    float* __restrict__ ycur,
    float* __restrict__ ksum,
    float* __restrict__ rk,
    int rkIdx, int s, float csv, float tmul, float tadd) {
  __shared__ float xs[128];
  __shared__ float red[8][256];
  const int tid = threadIdx.x;
  const int cb = blockIdx.x, rc = blockIdx.y;
  const int j0 = rc * 128;
  const float dtv = tptr[0] * (1.0f / STEPS);

  if (tid < 128) {
    const int j = j0 + tid;
    float xv;
    if (mode == 0) {                       // FIRST: x1 = sig(h)
      xv = sigf(ycur[j]);
    } else {
      float ssum = 0.f;
#pragma unroll 8
      for (int r = 0; r < 32; ++r) ssum += part_in[(r << 12) + j];
      if (mode == 1) {                     // P2: u1 = red + cpart1; x2 = sig(u1)
        const float u = ssum + cpart[j];
        if (cb == 0) u1[j] = u;
        xv = sigf(u);
      } else if (mode == 2) {              // P3: f = red + cpart2; v1 = s0'(ys)*f
        const float fv = ssum + cpart[j];
        if (cb == 0) fcur[j] = fv;
        float ys = ycur[j];
        if (csv != 0.f) ys = fmaf(csv * dtv, fprev[j], ys);
        const float s0 = sigf(ys);
        xv = s0 * (1.f - s0) * fv;
      } else if (mode == 3) {              // P4: du1 = red; v2 = s1'(u1)*du1; RK
        if (cb == 0) {
          const float fc = fcur[j];
          if (s == 0)      ksum[j] = fc;
          else if (s < 3)  ksum[j] = fmaf(2.f, fc, ksum[j]);
          else             ycur[j] = fmaf(dtv * (1.f / 6.f), ksum[j] + fc, ycur[j]);
        }
        const float s1 = sigf(u1[j]);
        xv = s1 * (1.f - s1) * ssum;
      } else {                             // PD: df = red; rk += df^2; x1 next
        float v = ssum * ssum;
#pragma unroll
        for (int off = 32; off >= 1; off >>= 1) v += __shfl_down(v, off);
        if (cb == 0 && (tid & 63) == 0) atomicAdd(&rk[rkIdx], v);
        float ys = ycur[j];
        if (csv != 0.f) ys = fmaf(csv * dtv, fprev[j], ys);
        xv = sigf(ys);
      }
    }
    xs[tid] = xv;
  }
  __syncthreads();

  const int cg = tid & 31, rg = tid >> 5;
  const unsigned short* __restrict__ wbase =
      Wbf + (size_t)j0 * N + cb * 256 + cg * 8;
  float a[8] = {0,0,0,0,0,0,0,0};
#pragma unroll
  for (int k = 0; k < 16; ++k) {
    const int r = rg + (k << 3);
    const float xv = xs[r];
    const us8 w = *reinterpret_cast<const us8*>(wbase + (size_t)r * N);
#pragma unroll
    for (int e = 0; e < 8; ++e) a[e] = fmaf(bf2f(w[e]), xv, a[e]);
  }
  if (rc == 31 && rg == 0) {               // t-row contribution
    const float coef = fmaf(tmul, dtv, tadd);
    const us8 w = *reinterpret_cast<const us8*>(
        Wbf + (size_t)N * N + cb * 256 + cg * 8);
#pragma unroll
    for (int e = 0; e < 8; ++e) a[e] = fmaf(bf2f(w[e]), coef, a[e]);
  }
#pragma unroll
  for (int e = 0; e < 8; ++e) red[rg][cg * 8 + e] = a[e];
  __syncthreads();
  float ssum = 0.f;
#pragma unroll
  for (int g = 0; g < 8; ++g) ssum += red[g][tid];
  part_out[(rc << 12) + cb * 256 + tid] = ssum;
}

// Reduce the final P4 partials -> rk[15]; copy ycur -> out.
__global__ __launch_bounds__(128) void k_last(const float* __restrict__ part_in,
                                              const float* __restrict__ ycur,
                                              float* __restrict__ rk,
                                              float* __restrict__ out) {
  const int tid = threadIdx.x;
  const int j = blockIdx.x * 128 + tid;
  float df = 0.f;
#pragma unroll 8
  for (int r = 0; r < 32; ++r) df += part_in[(r << 12) + j];
  float v = df * df;
#pragma unroll
  for (int off = 32; off >= 1; off >>= 1) v += __shfl_down(v, off);
  if ((tid & 63) == 0) atomicAdd(&rk[15], v);
  out[j] = ycur[j];
}

__global__ void k_out(const float* __restrict__ rk, const float* __restrict__ tptr,
                      float* __restrict__ out) {
  if (threadIdx.x == 0) {
    const float dtv = tptr[0] * (1.0f / STEPS);
    float r = 0.f;
    for (int st = 0; st < STEPS; ++st)
      r += rk[4 * st] + 2.f * rk[4 * st + 1] + 2.f * rk[4 * st + 2] + rk[4 * st + 3];
    out[N] = r * (dtv / 6.f) * (1.0f / N);
  }
}

// ---------------------------------------------------------------------------
extern "C" void kernel_launch(void* const* d_in, const int* in_sizes, int n_in,
                              void* d_out, int out_size, void* d_ws, size_t ws_size,
                              hipStream_t stream) {
  const float* h  = (const float*)d_in[0];
  const float* t  = (const float*)d_in[1];
  const float* c  = (const float*)d_in[2];
  const float* W1 = (const float*)d_in[3];
  const float* b1 = (const float*)d_in[4];
  const float* W2 = (const float*)d_in[5];
  const float* b2 = (const float*)d_in[6];
  float* out = (float*)d_out;

  // ws: W1bf | W2bf (bf16, 33.56 MB each) | fp32 buffers (~1.2 MB). Harness
  // ws_size ~336 MB (fill-kernel WRITE_SIZE evidence) >> 68.3 MB needed.
  char* ws = (char*)d_ws;
  const size_t wb = (size_t)NROWS * N * sizeof(unsigned short);
  unsigned short* W1bf = (unsigned short*)ws;
  unsigned short* W2bf = (unsigned short*)(ws + wb);
  float* fp = (float*)(ws + 2 * wb);
  float* partA = fp;                     // 32*4096
  float* partB = partA + 32 * N;
  float* cp1   = partB + 32 * N;
  float* cp2   = cp1 + N;
  float* u1    = cp2 + N;
  float* fb0   = u1 + N;
  float* fb1   = fb0 + N;
  float* ycur  = fb1 + N;
  float* ksum  = ycur + N;
  float* rk    = ksum + N;               // 16

  k_init<<<16, TPB, 0, stream>>>(h, b1, b2, ycur, cp1, cp2, rk);
  k_conv<<<dim3(NROWS, 2), TPB, 0, stream>>>(W1, W2, W1bf, W2bf);
  k_cpart<<<dim3(16, 8, 2), TPB, 0, stream>>>(W1, W2, c, cp1, cp2);

  const float csv[4] = {0.f, 0.5f, 0.5f, 1.f};
  float* bufs[2] = {partA, partB};
  int flip = 0;
  for (int i = 0; i < 16; ++i) {
    const int step = i >> 2, s = i & 3;
    const float tsv = (float)step + csv[s];
    float* fcur  = (i & 1) ? fb1 : fb0;
    float* fprev = (i & 1) ? fb0 : fb1;

    // P1: u1 partials = x1 @ W1_state   (FIRST for i=0, PD otherwise)
    {
      float* po = bufs[flip]; const float* pi = bufs[flip ^ 1]; flip ^= 1;
      if (i == 0)
        k_phase<<<dim3(16, 32), TPB, 0, stream>>>(0, W1bf, pi, po, cp1, t,
            u1, fcur, fprev, ycur, ksum, rk, 0, s, 0.f, 0.f, 0.f);
      else
        k_phase<<<dim3(16, 32), TPB, 0, stream>>>(4, W1bf, pi, po, cp1, t,
            u1, fcur, fprev, ycur, ksum, rk, i - 1, s, csv[s], tsv, 0.f);
    }
    // P2: f partials = sig(u1+cp1) @ W2_state
    {
      float* po = bufs[flip]; const float* pi = bufs[flip ^ 1]; flip ^= 1;
      k_phase<<<dim3(16, 32), TPB, 0, stream>>>(1, W2bf, pi, po, cp1, t,
          u1, fcur, fprev, ycur, ksum, rk, 0, s, csv[s], tsv, 0.f);
    }
    // P3: du1 partials = (sig'(ys)*f) @ W1_state, t-coef 1
    {
      float* po = bufs[flip]; const float* pi = bufs[flip ^ 1]; flip ^= 1;
      k_phase<<<dim3(16, 32), TPB, 0, stream>>>(2, W1bf, pi, po, cp2, t,
          u1, fcur, fprev, ycur, ksum, rk, 0, s, csv[s], 0.f, 1.f);
    }
    // P4: df partials = (sig'(u1)*du1) @ W2_state, t-coef 1; RK bookkeeping
    {
      float* po = bufs[flip]; const float* pi = bufs[flip ^ 1]; flip ^= 1;
      k_phase<<<dim3(16, 32), TPB, 0, stream>>>(3, W2bf, pi, po, cp2, t,
          u1, fcur, fprev, ycur, ksum, rk, 0, s, csv[s], 0.f, 1.f);
    }
  }
  k_last<<<32, 128, 0, stream>>>(bufs[flip ^ 1], ycur, rk, out);
  k_out<<<1, 64, 0, stream>>>(rk, t, out);
}